// Round 3
// baseline (333.905 us; speedup 1.0000x reference)
//
#include <hip/hip_runtime.h>
#include <hip/hip_bf16.h>

#define EPS 1e-10f
#define GRID1 2048   // 8 blocks/CU * 256 CU -> fully resident
#define BLOCK 256

// R2 post-mortem: 2048 same-address device-scope atomicAdds serialized at the
// coherence point (~120 us tail) dominated both R1 and R2 identically.
// R3: two-stage reduction -- stage 1 writes per-block partials to d_ws (no
// atomics), stage 2 (one block) reduces 2048 partials and writes out.

__global__ __launch_bounds__(BLOCK) void sparse_loss_stage1(
    const float* __restrict__ pred,
    const int* __restrict__ y,
    const int* __restrict__ lamda_p,
    float* __restrict__ partials,   // [GRID1]
    long long nvec,                 // number of float4 groups
    long long total) {              // total element count
  const float lam = (float)(*lamda_p);  // uniform scalar load

  float acc = 0.0f;  // accumulates +coef*log(arg); sign applied in stage 2

  const long long tid = (long long)blockIdx.x * blockDim.x + threadIdx.x;
  const long long stride = (long long)gridDim.x * blockDim.x;

  const float4* __restrict__ pv = reinterpret_cast<const float4*>(pred);
  const int4* __restrict__ yv = reinterpret_cast<const int4*>(y);

  long long i = tid;

#define ELEM(P, Y)                                              \
  {                                                             \
    const bool z = ((Y) == 0);                                  \
    const float a = EPS + (z ? (1.0f - (P)) : (P));             \
    const float c = z ? 1.0f : lam;                             \
    acc = fmaf(c, __logf(a), acc);                              \
  }
#define VEC4(P, Y)                                              \
  ELEM(P.x, Y.x) ELEM(P.y, Y.y) ELEM(P.z, Y.z) ELEM(P.w, Y.w)

  // main: 8 x 16B loads issued back-to-back, then 16 elems computed
  for (; i + 3 * stride < nvec; i += 4 * stride) {
    float4 p0 = pv[i];
    float4 p1 = pv[i + stride];
    float4 p2 = pv[i + 2 * stride];
    float4 p3 = pv[i + 3 * stride];
    int4 y0 = yv[i];
    int4 y1 = yv[i + stride];
    int4 y2 = yv[i + 2 * stride];
    int4 y3 = yv[i + 3 * stride];
    VEC4(p0, y0)
    VEC4(p1, y1)
    VEC4(p2, y2)
    VEC4(p3, y3)
  }

  // remainder vec4 groups
  for (; i < nvec; i += stride) {
    float4 p = pv[i];
    int4 yy = yv[i];
    VEC4(p, yy)
  }

  // scalar tail (total % 4 != 0 -- not the case here, but cheap)
  for (long long j = nvec * 4 + tid; j < total; j += stride) {
    const float p = pred[j];
    ELEM(p, y[j])
  }
#undef VEC4
#undef ELEM

  // wave64 butterfly reduce
  for (int off = 32; off > 0; off >>= 1)
    acc += __shfl_down(acc, off, 64);

  __shared__ float ssum[4];  // 256 threads = 4 waves
  const int lane = threadIdx.x & 63;
  const int wave = threadIdx.x >> 6;
  if (lane == 0) ssum[wave] = acc;
  __syncthreads();

  if (threadIdx.x == 0)
    partials[blockIdx.x] = ssum[0] + ssum[1] + ssum[2] + ssum[3];
}

__global__ __launch_bounds__(BLOCK) void sparse_loss_stage2(
    const float* __restrict__ partials,  // [GRID1]
    float* __restrict__ out,
    float inv_total) {
  float acc = 0.0f;
  for (int i = threadIdx.x; i < GRID1; i += BLOCK)
    acc += partials[i];

  for (int off = 32; off > 0; off >>= 1)
    acc += __shfl_down(acc, off, 64);

  __shared__ float ssum[4];
  const int lane = threadIdx.x & 63;
  const int wave = threadIdx.x >> 6;
  if (lane == 0) ssum[wave] = acc;
  __syncthreads();

  if (threadIdx.x == 0) {
    // loss = -mean
    out[0] = -(ssum[0] + ssum[1] + ssum[2] + ssum[3]) * inv_total;
  }
}

extern "C" void kernel_launch(void* const* d_in, const int* in_sizes, int n_in,
                              void* d_out, int out_size, void* d_ws, size_t ws_size,
                              hipStream_t stream) {
  const float* pred = (const float*)d_in[0];
  const int* y = (const int*)d_in[1];
  const int* lamda = (const int*)d_in[2];
  float* out = (float*)d_out;
  float* partials = (float*)d_ws;  // 2048 floats = 8 KB scratch

  const long long total = (long long)in_sizes[0];
  const long long nvec = total / 4;
  const float inv_total = 1.0f / (float)total;

  sparse_loss_stage1<<<GRID1, BLOCK, 0, stream>>>(pred, y, lamda, partials,
                                                  nvec, total);
  sparse_loss_stage2<<<1, BLOCK, 0, stream>>>(partials, out, inv_total);
}

// Round 4
// 330.067 us; speedup vs baseline: 1.0116x; 1.0116x over previous
//
#include <hip/hip_runtime.h>
#include <hip/hip_bf16.h>

#define EPS 1e-10f
#define BLOCK 256
#define GRID1 2048
#define TILE_VEC (BLOCK * 8)  // 2048 float4 groups = 32 KB pred + 32 KB y per tile

// R3 post-mortem: atomic theory falsified (no-atomic stage1 still 127us @1.3TB/s).
// Real issue: VGPR=32 means the "unroll" serialized loads (payload alone needs
// 32 regs). R4 forces true MLP: 16 loads (256 B/thread) into named register
// arrays before first use, contiguous 32KB block tiles, 32-bit offset math.

__global__ __launch_bounds__(BLOCK) void sparse_loss_stage1(
    const float* __restrict__ pred,
    const int* __restrict__ y,
    const int* __restrict__ lamda_p,
    float* __restrict__ partials,   // [GRID1]
    long long nvec,                 // number of float4 groups
    long long total) {              // total element count
  const float lam = (float)(*lamda_p);
  float acc = 0.0f;  // accumulates +coef*log(arg); sign applied in stage 2

  const float4* __restrict__ pv = reinterpret_cast<const float4*>(pred);
  const int4* __restrict__ yv = reinterpret_cast<const int4*>(y);

  const long long ntiles = (nvec + TILE_VEC - 1) / TILE_VEC;
  const int tid = threadIdx.x;

#define ELEM(P, Y)                                              \
  {                                                             \
    const bool z = ((Y) == 0);                                  \
    const float a = EPS + (z ? (1.0f - (P)) : (P));             \
    const float c = z ? 1.0f : lam;                             \
    acc = fmaf(c, __logf(a), acc);                              \
  }

  for (long long tile = blockIdx.x; tile < ntiles; tile += gridDim.x) {
    const long long base = tile * TILE_VEC;
    const float4* __restrict__ pt = pv + base;
    const int4* __restrict__ yt = yv + base;
    const long long rem = nvec - base;

    if (rem >= TILE_VEC) {
      // 16 independent coalesced loads, all issued before first use.
      float4 p[8];
      int4 yy[8];
#pragma unroll
      for (int k = 0; k < 8; ++k) p[k] = pt[tid + BLOCK * k];
#pragma unroll
      for (int k = 0; k < 8; ++k) yy[k] = yt[tid + BLOCK * k];
#pragma unroll
      for (int k = 0; k < 8; ++k) {
        ELEM(p[k].x, yy[k].x)
        ELEM(p[k].y, yy[k].y)
        ELEM(p[k].z, yy[k].z)
        ELEM(p[k].w, yy[k].w)
      }
    } else {
      for (long long j = tid; j < rem; j += BLOCK) {
        const float4 p = pt[j];
        const int4 yy = yt[j];
        ELEM(p.x, yy.x)
        ELEM(p.y, yy.y)
        ELEM(p.z, yy.z)
        ELEM(p.w, yy.w)
      }
    }
  }

  // scalar tail (total % 4 != 0 -- not the case here, but cheap)
  const long long gtid = (long long)blockIdx.x * BLOCK + tid;
  const long long gstride = (long long)gridDim.x * BLOCK;
  for (long long j = nvec * 4 + gtid; j < total; j += gstride) {
    const float p = pred[j];
    ELEM(p, y[j])
  }
#undef ELEM

  // wave64 butterfly reduce
  for (int off = 32; off > 0; off >>= 1)
    acc += __shfl_down(acc, off, 64);

  __shared__ float ssum[4];
  const int lane = tid & 63;
  const int wave = tid >> 6;
  if (lane == 0) ssum[wave] = acc;
  __syncthreads();

  if (tid == 0)
    partials[blockIdx.x] = ssum[0] + ssum[1] + ssum[2] + ssum[3];
}

__global__ __launch_bounds__(BLOCK) void sparse_loss_stage2(
    const float* __restrict__ partials,  // [GRID1]
    float* __restrict__ out,
    float inv_total) {
  float acc = 0.0f;
  for (int i = threadIdx.x; i < GRID1; i += BLOCK)
    acc += partials[i];

  for (int off = 32; off > 0; off >>= 1)
    acc += __shfl_down(acc, off, 64);

  __shared__ float ssum[4];
  const int lane = threadIdx.x & 63;
  const int wave = threadIdx.x >> 6;
  if (lane == 0) ssum[wave] = acc;
  __syncthreads();

  if (threadIdx.x == 0)
    out[0] = -(ssum[0] + ssum[1] + ssum[2] + ssum[3]) * inv_total;
}

extern "C" void kernel_launch(void* const* d_in, const int* in_sizes, int n_in,
                              void* d_out, int out_size, void* d_ws, size_t ws_size,
                              hipStream_t stream) {
  const float* pred = (const float*)d_in[0];
  const int* y = (const int*)d_in[1];
  const int* lamda = (const int*)d_in[2];
  float* out = (float*)d_out;
  float* partials = (float*)d_ws;  // 2048 floats = 8 KB scratch

  const long long total = (long long)in_sizes[0];
  const long long nvec = total / 4;
  const float inv_total = 1.0f / (float)total;

  sparse_loss_stage1<<<GRID1, BLOCK, 0, stream>>>(pred, y, lamda, partials,
                                                  nvec, total);
  sparse_loss_stage2<<<1, BLOCK, 0, stream>>>(partials, out, inv_total);
}